// Round 11
// baseline (16397.905 us; speedup 1.0000x reference)
//
#include <hip/hip_runtime.h>
#include <hip/hip_bf16.h>
#include <stdint.h>

typedef unsigned short u16;
typedef unsigned int u32;
typedef float f32x4 __attribute__((ext_vector_type(4)));
typedef short bf16x8 __attribute__((ext_vector_type(8)));
typedef u16 u16x4 __attribute__((ext_vector_type(4)));

__device__ __forceinline__ float b2f(u16 u){ union{u32 i; float f;} c; c.i=((u32)u)<<16; return c.f; }
__device__ __forceinline__ u16 f2b(float f){ __hip_bfloat16 h=__float2bfloat16(f); return *(u16*)&h; }
__device__ __forceinline__ float sigm(float x){ return 1.f/(1.f+__expf(-x)); }
__device__ __forceinline__ float tanh_(float x){ return 1.f - 2.f/(1.f+__expf(2.f*x)); }
__device__ __forceinline__ float qw(float v, float s){ return (v==v && fabsf(v)<1e30f) ? v : s; }

template<bool F32> __device__ __forceinline__ float ldsc(const void* p, size_t i){
  if constexpr (F32) return ((const float*)p)[i];
  else               return b2f(((const u16*)p)[i]);
}
template<bool F32> __device__ __forceinline__ f32x4 ldf4(const void* p, size_t i){
  if constexpr (F32) return *(const f32x4*)((const float*)p + i);
  else { u16x4 v = *(const u16x4*)((const u16*)p + i); f32x4 r;
         #pragma unroll
         for (int j=0;j<4;++j) r[j]=b2f(v[j]); return r; }
}
template<bool F32> __device__ __forceinline__ void stf4(void* p, size_t i, f32x4 v){
  if constexpr (F32) *(f32x4*)((float*)p + i) = v;
  else { u16x4 o;
         #pragma unroll
         for (int j=0;j<4;++j) o[j]=f2b(v[j]); *(u16x4*)((u16*)p + i) = o; }
}
template<bool F32> __device__ __forceinline__ bf16x8 ld8(const void* p, size_t ix){
  if constexpr (F32){
    const float* f = (const float*)p + ix;
    f32x4 a = *(const f32x4*)f, b = *(const f32x4*)(f+4);
    bf16x8 r;
    #pragma unroll
    for (int j=0;j<4;++j){ r[j]=(short)f2b(a[j]); r[4+j]=(short)f2b(b[j]); }
    return r;
  } else {
    return *(const bf16x8*)((const u16*)p + ix);
  }
}

constexpr size_t OT = 0;           // x_time   (8,128,256,256)
constexpr size_t OC = 67108864;    // x_central(8,128,256)
constexpr size_t OF = 67371008;    // x_freq   (8,128,256,256)
constexpr int RS = 264;            // LDS row stride (u16)

struct Args {
  const void *xt, *xc, *xf;
  const void *bi[5], *bh[5];
  const void *b_cent, *b_freq;
  const u16 *pg[5];                // packed gate weights  [48 ct][16 kt][64 lane][8]
  const u16 *po[5];                // packed out-proj wts  [16 ct][ 8 kt][64 lane][8]
  void *out;
};

template<int MODE, bool F32>
__device__ __forceinline__ bf16x8 stage_ld(const Args& A, const void* out, int n0, int r, int m, int c){
  if (MODE==0){ const int n=n0+r;
    return ld8<F32>(A.xt, ((size_t)(n>>8)<<23)+((size_t)m<<16)+((size_t)(n&255)<<8)+c); }
  else if (MODE==1 || MODE==2){ const int n=n0+r;
    return ld8<F32>(A.xt, ((size_t)n<<16)+((size_t)m<<8)+c); }
  else if (MODE==3){ const int n=n0+(r&7);
    return ld8<F32>(A.xc, ((size_t)n<<15)+((size_t)m<<8)+c); }
  else { const int n=n0+r;
    return ld8<F32>(out, OF+((size_t)n<<16)+((size_t)m<<8)+c); }
}

// 512-thread (8-wave) transposed-MFMA GRU, 16 rows/block. Spill-free: fits 128 VGPR.
// Wave w owns out-cols [(w*2+dt)*16 .. +16), dt in {0,1}, per gate.
// MODE: 0=t 1=ff 2=fb(rev -> OF scratch) 3=c 4=f(stage premerged OF)
template<int MODE, bool F32>
__device__ void grumm(const Args& A, u16* xb0, u16* xb1, u16* xb2, u16* hb,
                      float* pbA, float* pbB, float* pbo, int n0, int L){
  constexpr float SENT = 1000.f * (MODE+1);
  const u16* __restrict__ PG = A.pg[MODE];
  const u16* __restrict__ PO = A.po[MODE];
  void* const out = A.out;
  const int tid=threadIdx.x, lane=tid&63, w=tid>>6, l15=lane&15, l4=lane>>4;

  if (tid < 256){
    pbA[tid]     = ldsc<F32>(A.bi[MODE],tid)     + ldsc<F32>(A.bh[MODE],tid);
    pbA[256+tid] = ldsc<F32>(A.bi[MODE],256+tid) + ldsc<F32>(A.bh[MODE],256+tid);
    pbA[512+tid] = ldsc<F32>(A.bi[MODE],512+tid);
    pbB[tid]     = ldsc<F32>(A.bh[MODE],512+tid);
    pbo[tid]     = (MODE==3)? ldsc<F32>(A.b_cent,tid) : (MODE==4)? ldsc<F32>(A.b_freq,tid) : 0.f;
  }
  for (int i=tid; i<16*RS; i+=512) hb[i]=0;

  f32x4 hC[2];
  hC[0]=f32x4{0.f,0.f,0.f,0.f}; hC[1]=f32x4{0.f,0.f,0.f,0.f};

  // weight ring: 4 slots x 2 frags = 32 VGPR (chunk c: g=c>>4, kt=c&15; ct=g*16+w*2+dt)
  bf16x8 rng[4][2];
  #pragma unroll
  for (int c=0; c<4; ++c){
    #pragma unroll
    for (int dt=0; dt<2; ++dt){
      const int ct = (c>>4)*16 + w*2 + dt;
      rng[c][dt] = *(const bf16x8*)(PG + ((size_t)(ct*16+(c&15))*64 + lane)*8);
    }
  }

  // x staging: 32 threads/row; triple-buffered (load for step s lands s-2 early)
  const int sr = tid>>5, sc = (tid&31)*8;
  {
    const int m0 = (MODE==2)? (L-1) : 0;
    bf16x8 t0 = stage_ld<MODE,F32>(A,out,n0,sr,m0,sc);
    *(bf16x8*)(xb0 + sr*RS + sc) = t0;
  }
  bf16x8 sP, sN;            // sP: x(it+1) in regs; sN: x(it+2) being loaded
  if (L>1){
    const int m1 = (MODE==2)? (L-2) : 1;
    sP = stage_ld<MODE,F32>(A,out,n0,sr,m1,sc);
  }
  __syncthreads();

  u16 *cur=xb0, *nxt=xb1, *nx2=xb2;

  for (int it=0; it<L; ++it){
    const int m = (MODE==2)? (L-1-it) : it;
    const int n = n0 + l15;
    f32x4 eo[2];

    // ---- gate MFMA, ring-4 prefetch (L2-covered) ----
    f32x4 Cr[2],Cz[2],Cnx[2],Cnh[2];
    #pragma unroll
    for (int dt=0;dt<2;++dt){ Cr[dt]=f32x4{0,0,0,0}; Cz[dt]=f32x4{0,0,0,0};
                              Cnx[dt]=f32x4{0,0,0,0}; Cnh[dt]=f32x4{0,0,0,0}; }
    #pragma unroll
    for (int c=0; c<48; ++c){
      const int g = c>>4, kt = c&15;
      const u16* sld = (kt<8)? cur : hb;
      bf16x8 ab = *(const bf16x8*)(sld + l15*RS + (kt&7)*32 + l4*8);
      #pragma unroll
      for (int dt=0; dt<2; ++dt){
        f32x4& acc = (g==0)? Cr[dt] : (g==1)? Cz[dt] : (kt<8)? Cnx[dt] : Cnh[dt];
        acc = __builtin_amdgcn_mfma_f32_16x16x32_bf16(rng[c&3][dt], ab, acc, 0,0,0);
      }
      const int rc = (c+4)%48;   // refill slot c&3 (step-invariant weights wrap)
      #pragma unroll
      for (int dt=0; dt<2; ++dt){
        const int ct = (rc>>4)*16 + w*2 + dt;
        rng[c&3][dt] = *(const bf16x8*)(PG + ((size_t)(ct*16+(rc&15))*64 + lane)*8);
      }
    }

    // ---- activations ----
    #pragma unroll
    for (int dt=0; dt<2; ++dt){
      const int cb = (w*2+dt)*16 + l4*4;
      f32x4 bR  = *(const f32x4*)&pbA[cb];
      f32x4 bZ  = *(const f32x4*)&pbA[256+cb];
      f32x4 bNX = *(const f32x4*)&pbA[512+cb];
      f32x4 bNH = *(const f32x4*)&pbB[cb];
      #pragma unroll
      for (int i=0;i<4;++i){
        const float r_ = sigm(Cr[dt][i] + bR[i]);
        const float z_ = sigm(Cz[dt][i] + bZ[i]);
        const float nn = tanh_(Cnx[dt][i] + bNX[i] + r_*(Cnh[dt][i] + bNH[i]));
        hC[dt][i] = (1.f - z_)*nn + z_*hC[dt][i];
      }
    }

    __syncthreads();                 // bar1: gate readers of hb/cur done
    #pragma unroll
    for (int dt=0; dt<2; ++dt){
      const int cb = (w*2+dt)*16 + l4*4;
      u16x4 hw;
      #pragma unroll
      for (int i=0;i<4;++i) hw[i]=f2b(hC[dt][i]);
      *(u16x4*)(hb + l15*RS + cb) = hw;
    }
    if (it+1 < L) *(bf16x8*)(nxt + sr*RS + sc) = sP;   // sP loaded >=1 full step ago
    __syncthreads();                 // bar2: h + next x visible

    // ---- fused output projection (wf loads inline; eo injected at kt==4) ----
    f32x4 Co[2];
    Co[0]=f32x4{0,0,0,0}; Co[1]=f32x4{0,0,0,0};
    #pragma unroll
    for (int kt=0; kt<8; ++kt){
      bf16x8 hf = *(const bf16x8*)(hb + l15*RS + kt*32 + l4*8);
      bf16x8 w0 = *(const bf16x8*)(PO + ((size_t)((w*2+0)*8+kt)*64 + lane)*8);
      bf16x8 w1 = *(const bf16x8*)(PO + ((size_t)((w*2+1)*8+kt)*64 + lane)*8);
      if (kt==4){
        #pragma unroll
        for (int dt=0; dt<2; ++dt){
          const int d0 = (w*2+dt)*16 + l4*4;
          if (MODE==0){
            const size_t gix = ((size_t)(n>>8)<<23)+((size_t)m<<16)+((size_t)(n&255)<<8)+d0;
            eo[dt] = ldf4<F32>(out, OT+gix);
          } else if (MODE==1){
            const size_t gix = ((size_t)n<<16)+((size_t)m<<8)+d0;
            eo[dt] = ldf4<F32>(out, OT+gix);
          } else if (MODE==3){
            if (l15 < 8) eo[dt] = ldf4<F32>(A.xc, ((size_t)n<<15)+((size_t)m<<8)+d0);
          } else if (MODE==4){
            eo[dt] = ldf4<F32>(A.xf, ((size_t)n<<16)+((size_t)m<<8)+d0);
          }
        }
      }
      Co[0] = __builtin_amdgcn_mfma_f32_16x16x32_bf16(w0, hf, Co[0], 0,0,0);
      Co[1] = __builtin_amdgcn_mfma_f32_16x16x32_bf16(w1, hf, Co[1], 0,0,0);
    }

    // sN (x for it+2): issued AFTER all PV loads -> no wait before next step's
    // h-write drains it (vmcnt is FIFO; keep slow loads youngest).
    if (it+2 < L){
      const int m2 = (MODE==2)? (L-3-it) : (it+2);
      sN = stage_ld<MODE,F32>(A,out,n0,sr,m2,sc);
    }

    // ---- epilogue: 2 coalesced f32x4 stores/RMWs ----
    #pragma unroll
    for (int dt=0; dt<2; ++dt){
      const int d0 = (w*2+dt)*16 + l4*4;
      f32x4 v = Co[dt];
      if (MODE==0){
        const size_t gix = ((size_t)(n>>8)<<23)+((size_t)m<<16)+((size_t)(n&255)<<8)+d0;
        #pragma unroll
        for (int i=0;i<4;++i) v[i]=qw(eo[dt][i]+v[i],SENT);
        stf4<F32>(out, OT+gix, v);
      } else if (MODE==1){
        const size_t gix = ((size_t)n<<16)+((size_t)m<<8)+d0;
        #pragma unroll
        for (int i=0;i<4;++i) v[i]=qw(eo[dt][i]+v[i],SENT);
        stf4<F32>(out, OT+gix, v);
      } else if (MODE==2){
        const size_t gix = ((size_t)n<<16)+((size_t)m<<8)+d0;
        #pragma unroll
        for (int i=0;i<4;++i) v[i]=qw(v[i],SENT);
        stf4<F32>(out, OF+gix, v);
      } else if (MODE==3){
        if (l15 < 8){
          const size_t lix = ((size_t)n<<15)+((size_t)m<<8)+d0;
          f32x4 bo = *(const f32x4*)&pbo[d0];
          #pragma unroll
          for (int i=0;i<4;++i) v[i]=qw(eo[dt][i]+bo[i]+v[i],SENT);
          stf4<F32>(out, OC+lix, v);
        }
      } else {
        const size_t gix = ((size_t)n<<16)+((size_t)m<<8)+d0;
        f32x4 bo = *(const f32x4*)&pbo[d0];
        #pragma unroll
        for (int i=0;i<4;++i) v[i]=qw(eo[dt][i]+bo[i]+v[i],SENT);
        stf4<F32>(out, OF+gix, v);
      }
    }

    sP = sN;
    u16* t_ = cur; cur = nxt; nxt = nx2; nx2 = t_;
  }
}

__global__ void __launch_bounds__(64) k_detect(const void* w, int* flagp){
  if (threadIdx.x==0 && blockIdx.x==0){
    const u32* p = (const u32*)w;
    int cnt = 0;
    for (int i=0;i<128;++i){
      const float v = b2f((u16)(p[i]&0xFFFFu));
      if (!(fabsf(v) <= 1e3f)) cnt++;
    }
    *flagp = (cnt>0) ? 1 : 0;
  }
}

#define GRU_LDS \
  __shared__ u16 xb0[16*RS]; __shared__ u16 xb1[16*RS]; __shared__ u16 xb2[16*RS]; \
  __shared__ u16 hb[16*RS]; \
  __shared__ float pbA[768]; __shared__ float pbB[256]; __shared__ float pbo[256];

__global__ void __launch_bounds__(512) k1(Args A, const int* fl){   // gru_t(128) + gru_c(1)
  GRU_LDS
  const bool f32 = (*fl)!=0;
  if (blockIdx.x < 128){
    if (f32) grumm<0,true >(A,xb0,xb1,xb2,hb,pbA,pbB,pbo, blockIdx.x*16, 128);
    else     grumm<0,false>(A,xb0,xb1,xb2,hb,pbA,pbB,pbo, blockIdx.x*16, 128);
  } else {
    if (f32) grumm<3,true >(A,xb0,xb1,xb2,hb,pbA,pbB,pbo, 0, 128);
    else     grumm<3,false>(A,xb0,xb1,xb2,hb,pbA,pbB,pbo, 0, 128);
  }
}
__global__ void __launch_bounds__(512) k2(Args A, const int* fl){   // gru_ff(64) + gru_fb(64)
  GRU_LDS
  const bool f32 = (*fl)!=0;
  if (blockIdx.x < 64){
    if (f32) grumm<1,true >(A,xb0,xb1,xb2,hb,pbA,pbB,pbo, blockIdx.x*16, 256);
    else     grumm<1,false>(A,xb0,xb1,xb2,hb,pbA,pbB,pbo, blockIdx.x*16, 256);
  } else {
    if (f32) grumm<2,true >(A,xb0,xb1,xb2,hb,pbA,pbB,pbo, (blockIdx.x-64)*16, 256);
    else     grumm<2,false>(A,xb0,xb1,xb2,hb,pbA,pbB,pbo, (blockIdx.x-64)*16, 256);
  }
}
__global__ void __launch_bounds__(512) k3(Args A, const int* fl){   // gru_f(64)
  GRU_LDS
  if ((*fl)!=0) grumm<4,true >(A,xb0,xb1,xb2,hb,pbA,pbB,pbo, blockIdx.x*16, 256);
  else          grumm<4,false>(A,xb0,xb1,xb2,hb,pbA,pbB,pbo, blockIdx.x*16, 256);
}

template<bool F32>
__device__ void merge_body(const void* xf, void* out){
  const size_t i4 = ((size_t)blockIdx.x*256 + threadIdx.x)*4;   // < 67,108,864
  const int n  = (int)(i4 >> 16);
  const int d  = (int)(i4 & 255);
  f32x4 t; f32x4 a = ldf4<F32>(out, OT+i4), b = ldf4<F32>(out, OF+i4);
  f32x4 xfv = ldf4<F32>(xf, i4), cv = ldf4<F32>(out, OC+((size_t)n<<8)+d);
  f32x4 x;
  #pragma unroll
  for (int j=0;j<4;++j){ t[j]=qw(a[j]+b[j],6000.f); x[j]=qw(t[j]+xfv[j]+cv[j],6000.f); }
  stf4<F32>(out, OT+i4, t);
  stf4<F32>(out, OF+i4, x);
}
__global__ void __launch_bounds__(256) k_merge(const void* xf, void* out, const int* fl){
  if ((*fl)!=0) merge_body<true >(xf, out);
  else          merge_body<false>(xf, out);
}

template<bool F32>
__device__ void init_body(const void* xt, const void* bt, void* out){
  const size_t i4 = ((size_t)blockIdx.x*256 + threadIdx.x)*4;
  f32x4 x = ldf4<F32>(xt, i4), b = ldf4<F32>(bt, i4&255);
  f32x4 v;
  #pragma unroll
  for (int j=0;j<4;++j) v[j]=qw(x[j]+b[j],7000.f);
  stf4<F32>(out, OT+i4, v);
}
__global__ void __launch_bounds__(256) k_init(const void* xt, const void* bt, void* out, const int* fl){
  if ((*fl)!=0) init_body<true >(xt, bt, out);
  else          init_body<false>(xt, bt, out);
}

__global__ void __launch_bounds__(256) k_pack_g(const void* Wi, const void* Wh,
                                                u16* __restrict__ dst, const int* fl){
  const bool f32 = (*fl)!=0;
  const int t = blockIdx.x*256 + threadIdx.x;
  if (t >= 49152) return;
  const int lane = t & 63, kt = (t>>6)&15, ct = t>>10;
  const int col = ct*16 + (lane&15);
  const int kb  = kt*32 + ((lane>>4)<<3);
  #pragma unroll
  for (int j=0;j<8;++j){
    const int k = kb + j;
    const size_t six = (k<256) ? ((size_t)col*256 + k) : ((size_t)col*256 + k - 256);
    const void* src = (k<256) ? Wi : Wh;
    const float v = f32 ? ldsc<true>(src,six) : ldsc<false>(src,six);
    dst[(size_t)t*8+j] = f2b(v);
  }
}

__global__ void __launch_bounds__(256) k_pack_o(const void* Wsrc, int ldk, int koff,
                                                u16* __restrict__ dst, const int* fl){
  const bool f32 = (*fl)!=0;
  const int t = blockIdx.x*256 + threadIdx.x;
  if (t >= 8192) return;
  const int lane = t & 63, kt = (t>>6)&7, ct = t>>9;
  const int d  = ct*16 + (lane&15);
  const int kb = kt*32 + ((lane>>4)<<3) + koff;
  #pragma unroll
  for (int j=0;j<8;++j){
    const float v = f32 ? ldsc<true>(Wsrc,(size_t)d*ldk+kb+j) : ldsc<false>(Wsrc,(size_t)d*ldk+kb+j);
    dst[(size_t)t*8+j] = f2b(v);
  }
}

extern "C" void kernel_launch(void* const* d_in, const int* in_sizes, int n_in,
                              void* d_out, int out_size, void* d_ws, size_t ws_size,
                              hipStream_t stream){
  if (ws_size < 4600000) return;

  const void* x_time = d_in[0];
  const void* x_cent = d_in[1];
  const void* x_freq = d_in[2];
  const void *Wi[5], *Wh[5], *bi[5], *bh[5];
  for (int i=0;i<5;++i){
    Wi[i]=d_in[5+4*i]; Wh[i]=d_in[6+4*i]; bi[i]=d_in[7+4*i]; bh[i]=d_in[8+4*i];
  }
  const void* W_time=d_in[25]; const void* b_time=d_in[26];
  const void* W_cent=d_in[27]; const void* b_cent=d_in[28];
  const void* W_freq=d_in[29]; const void* b_freq=d_in[30];

  u16* wsu = (u16*)d_ws;
  u16* pg[5]; u16* po[5];
  size_t off = 0;
  for (int i=0;i<5;++i){ pg[i]=wsu+off; off += 49152*8; }
  for (int i=0;i<5;++i){ po[i]=wsu+off; off += 8192*8; }
  int* flagp = (int*)((char*)d_ws + 4587520);

  dim3 blk(256);
  k_detect<<<1, 64, 0, stream>>>(Wi[0], flagp);

  for (int i=0;i<5;++i) k_pack_g<<<192, blk, 0, stream>>>(Wi[i], Wh[i], pg[i], flagp);
  k_pack_o<<<32, blk, 0, stream>>>(W_time, 768,   0, po[0], flagp);
  k_pack_o<<<32, blk, 0, stream>>>(W_time, 768, 256, po[1], flagp);
  k_pack_o<<<32, blk, 0, stream>>>(W_time, 768, 512, po[2], flagp);
  k_pack_o<<<32, blk, 0, stream>>>(W_cent, 256,   0, po[3], flagp);
  k_pack_o<<<32, blk, 0, stream>>>(W_freq, 256,   0, po[4], flagp);

  k_init<<<65536, blk, 0, stream>>>(x_time, b_time, d_out, flagp);

  Args A;
  A.xt=x_time; A.xc=x_cent; A.xf=x_freq;
  for (int i=0;i<5;++i){ A.bi[i]=bi[i]; A.bh[i]=bh[i]; A.pg[i]=pg[i]; A.po[i]=po[i]; }
  A.b_cent=b_cent; A.b_freq=b_freq;
  A.out=d_out;

  dim3 blk512(512);
  k1<<<129, blk512, 0, stream>>>(A, flagp);                 // t (RMW o_time) + c
  k2<<<128, blk512, 0, stream>>>(A, flagp);                 // ff (RMW o_time) + fb (-> OF scratch)
  k_merge<<<65536, blk, 0, stream>>>(x_freq, d_out, flagp); // o_time final; OF := xfs
  k3<<<64, blk512, 0, stream>>>(A, flagp);                  // f: stage xfs, write o_freq final
}

// Round 12
// 8411.970 us; speedup vs baseline: 1.9494x; 1.9494x over previous
//
#include <hip/hip_runtime.h>
#include <hip/hip_bf16.h>
#include <stdint.h>

typedef unsigned short u16;
typedef unsigned int u32;
typedef float f32x4 __attribute__((ext_vector_type(4)));
typedef short bf16x8 __attribute__((ext_vector_type(8)));
typedef u16 u16x4 __attribute__((ext_vector_type(4)));

__device__ __forceinline__ float b2f(u16 u){ union{u32 i; float f;} c; c.i=((u32)u)<<16; return c.f; }
__device__ __forceinline__ u16 f2b(float f){ __hip_bfloat16 h=__float2bfloat16(f); return *(u16*)&h; }
__device__ __forceinline__ float sigm(float x){ return 1.f/(1.f+__expf(-x)); }
__device__ __forceinline__ float tanh_(float x){ return 1.f - 2.f/(1.f+__expf(2.f*x)); }
__device__ __forceinline__ float qw(float v, float s){ return (v==v && fabsf(v)<1e30f) ? v : s; }

// async global->LDS DMA, 16B/lane (dest = wave-uniform base + lane*16, linear)
__device__ __forceinline__ void dma16(const void* g, void* l){
  __builtin_amdgcn_global_load_lds(
      (const __attribute__((address_space(1))) void*)g,
      (__attribute__((address_space(3))) void*)l, 16, 0, 0);
}

template<bool F32> __device__ __forceinline__ float ldsc(const void* p, size_t i){
  if constexpr (F32) return ((const float*)p)[i];
  else               return b2f(((const u16*)p)[i]);
}
template<bool F32> __device__ __forceinline__ f32x4 ldf4(const void* p, size_t i){
  if constexpr (F32) return *(const f32x4*)((const float*)p + i);
  else { u16x4 v = *(const u16x4*)((const u16*)p + i); f32x4 r;
         #pragma unroll
         for (int j=0;j<4;++j) r[j]=b2f(v[j]); return r; }
}
template<bool F32> __device__ __forceinline__ void stf4(void* p, size_t i, f32x4 v){
  if constexpr (F32) *(f32x4*)((float*)p + i) = v;
  else { u16x4 o;
         #pragma unroll
         for (int j=0;j<4;++j) o[j]=f2b(v[j]); *(u16x4*)((u16*)p + i) = o; }
}
template<bool F32> __device__ __forceinline__ bf16x8 ld8(const void* p, size_t ix){
  if constexpr (F32){
    const float* f = (const float*)p + ix;
    f32x4 a = *(const f32x4*)f, b = *(const f32x4*)(f+4);
    bf16x8 r;
    #pragma unroll
    for (int j=0;j<4;++j){ r[j]=(short)f2b(a[j]); r[4+j]=(short)f2b(b[j]); }
    return r;
  } else {
    return *(const bf16x8*)((const u16*)p + ix);
  }
}

constexpr size_t OT = 0;           // x_time   (8,128,256,256)
constexpr size_t OC = 67108864;    // x_central(8,128,256)
constexpr size_t OF = 67371008;    // x_freq   (8,128,256,256)
constexpr int RS = 264;            // LDS row stride (u16)

struct Args {
  const void *xt, *xc, *xf;
  const void *bi[5], *bh[5];
  const void *b_cent, *b_freq;
  const u16 *pg[5];                // packed gate weights  [48 ct][16 kt][64 lane][8]
  const u16 *po[5];                // packed out-proj wts  [16 ct][ 8 kt][64 lane][8]
  void *out;
};

template<int MODE, bool F32>
__device__ __forceinline__ bf16x8 stage_ld(const Args& A, const void* out, int n0, int r, int m, int c){
  if (MODE==0){ const int n=n0+r;
    return ld8<F32>(A.xt, ((size_t)(n>>8)<<23)+((size_t)m<<16)+((size_t)(n&255)<<8)+c); }
  else if (MODE==1 || MODE==2){ const int n=n0+r;
    return ld8<F32>(A.xt, ((size_t)n<<16)+((size_t)m<<8)+c); }
  else if (MODE==3){ const int n=n0+(r&7);
    return ld8<F32>(A.xc, ((size_t)n<<15)+((size_t)m<<8)+c); }
  else { const int n=n0+r;
    return ld8<F32>(out, OF+((size_t)n<<16)+((size_t)m<<8)+c); }
}

// 256-thread (4-wave) transposed-MFMA GRU, 16 rows/block.
// Wave w owns ct = g*16 + w*4 + dt (dt 0..3) per gate g.
// Gate weights stream through a wave-private 4-slot LDS ring via global_load_lds.
// MODE: 0=t 1=ff 2=fb(rev -> OF scratch) 3=c 4=f(stage premerged OF)
template<int MODE, bool F32>
__device__ void grumm(const Args& A, u16* wgt, u16* xb0, u16* xb1, u16* xb2, u16* hb,
                      float* pbA, float* pbB, float* pbo, int n0, int L){
  constexpr float SENT = 1000.f * (MODE+1);
  const u16* __restrict__ PG = A.pg[MODE];
  const u16* __restrict__ PO = A.po[MODE];
  void* const out = A.out;
  const int tid=threadIdx.x, lane=tid&63, w=tid>>6, l15=lane&15, l4=lane>>4;

  // biases -> LDS (fp32); h zero
  pbA[tid]     = ldsc<F32>(A.bi[MODE],tid)     + ldsc<F32>(A.bh[MODE],tid);
  pbA[256+tid] = ldsc<F32>(A.bi[MODE],256+tid) + ldsc<F32>(A.bh[MODE],256+tid);
  pbA[512+tid] = ldsc<F32>(A.bi[MODE],512+tid);
  pbB[tid]     = ldsc<F32>(A.bh[MODE],512+tid);
  pbo[tid]     = (MODE==3)? ldsc<F32>(A.b_cent,tid) : (MODE==4)? ldsc<F32>(A.b_freq,tid) : 0.f;
  for (int i=tid; i<16*RS; i+=256) hb[i]=0;

  f32x4 hC[4];
  #pragma unroll
  for (int dt=0;dt<4;++dt) hC[dt]=f32x4{0.f,0.f,0.f,0.f};

  // wave-private weight ring: 4 slots x 4 dt x 512 u16 (4KB/chunk)
  u16* mywgt = wgt + w*8192;
  auto issue_chunk = [&](int c, int s){
    const int g = c>>4, kt2 = c&15;
    #pragma unroll
    for (int dt=0; dt<4; ++dt){
      const int ct = g*16 + w*4 + dt;
      dma16(PG + ((size_t)(ct*16+kt2)*64 + lane)*8,
            mywgt + (s*4+dt)*512 + lane*8);
    }
  };

  // x staging: 16 threads/row, 16 u16 each (two bf16x8)
  const int sr = tid>>4, sc = (tid&15)*16;
  {
    const int m0 = (MODE==2)? (L-1) : 0;
    bf16x8 a0 = stage_ld<MODE,F32>(A,out,n0,sr,m0,sc);
    bf16x8 a1 = stage_ld<MODE,F32>(A,out,n0,sr,m0,sc+8);
    *(bf16x8*)(xb0 + sr*RS + sc)   = a0;
    *(bf16x8*)(xb0 + sr*RS + sc+8) = a1;
  }
  bf16x8 sP0, sP1, sN0, sN1;     // x(it+1) regs; x(it+2) in flight
  if (L>1){
    const int m1 = (MODE==2)? (L-2) : 1;
    sP0 = stage_ld<MODE,F32>(A,out,n0,sr,m1,sc);
    sP1 = stage_ld<MODE,F32>(A,out,n0,sr,m1,sc+8);
  }
  // prologue: fill ring slots 0..3 with chunks 0..3
  #pragma unroll
  for (int s=0; s<4; ++s) issue_chunk(s, s);
  __syncthreads();

  u16 *cur=xb0, *nxt=xb1, *nx2=xb2;

  for (int it=0; it<L; ++it){
    const int m = (MODE==2)? (L-1-it) : it;
    const int n = n0 + l15;
    f32x4 eo[4];

    f32x4 Cr[4],Cz[4],Cnx[4],Cnh[4];
    #pragma unroll
    for (int dt=0;dt<4;++dt){ Cr[dt]=f32x4{0,0,0,0}; Cz[dt]=f32x4{0,0,0,0};
                              Cnx[dt]=f32x4{0,0,0,0}; Cnh[dt]=f32x4{0,0,0,0}; }

    // ---- gate phases (acc target static per phase; ring slot static via s) ----
#define GPHASE(ACC, C0, NGRP, SRCSEL)                                          \
    _Pragma("unroll 1")                                                        \
    for (int grp=0; grp<(NGRP); ++grp){                                        \
      _Pragma("unroll")                                                        \
      for (int s=0; s<4; ++s){                                                 \
        const int c = (C0) + grp*4 + s;                                        \
        asm volatile("s_waitcnt vmcnt(12)" ::: "memory");                      \
        const int kt = c & 15;                                                 \
        const u16* sld = (SRCSEL);                                             \
        bf16x8 ab = *(const bf16x8*)(sld + l15*RS + (kt&7)*32 + l4*8);         \
        bf16x8 f0 = *(const bf16x8*)(mywgt + (s*4+0)*512 + lane*8);            \
        bf16x8 f1 = *(const bf16x8*)(mywgt + (s*4+1)*512 + lane*8);            \
        bf16x8 f2 = *(const bf16x8*)(mywgt + (s*4+2)*512 + lane*8);            \
        bf16x8 f3 = *(const bf16x8*)(mywgt + (s*4+3)*512 + lane*8);            \
        { int rc = c + 4; if (rc >= 48) rc -= 48; issue_chunk(rc, s); }        \
        ACC[0] = __builtin_amdgcn_mfma_f32_16x16x32_bf16(f0, ab, ACC[0],0,0,0);\
        ACC[1] = __builtin_amdgcn_mfma_f32_16x16x32_bf16(f1, ab, ACC[1],0,0,0);\
        ACC[2] = __builtin_amdgcn_mfma_f32_16x16x32_bf16(f2, ab, ACC[2],0,0,0);\
        ACC[3] = __builtin_amdgcn_mfma_f32_16x16x32_bf16(f3, ab, ACC[3],0,0,0);\
      } }

    GPHASE(Cr,   0, 4, (kt<8)? cur : hb)   // g=0, kt 0..15
    GPHASE(Cz,  16, 4, (kt<8)? cur : hb)   // g=1
    GPHASE(Cnx, 32, 2, cur)                // g=2, kt 0..7 (x part)
    GPHASE(Cnh, 40, 2, hb)                 // g=2, kt 8..15 (h part)
#undef GPHASE

    // ---- activations ----
    #pragma unroll
    for (int dt=0; dt<4; ++dt){
      const int cb = (w*4+dt)*16 + l4*4;
      f32x4 bR  = *(const f32x4*)&pbA[cb];
      f32x4 bZ  = *(const f32x4*)&pbA[256+cb];
      f32x4 bNX = *(const f32x4*)&pbA[512+cb];
      f32x4 bNH = *(const f32x4*)&pbB[cb];
      #pragma unroll
      for (int i=0;i<4;++i){
        const float r_ = sigm(Cr[dt][i] + bR[i]);
        const float z_ = sigm(Cz[dt][i] + bZ[i]);
        const float nn = tanh_(Cnx[dt][i] + bNX[i] + r_*(Cnh[dt][i] + bNH[i]));
        hC[dt][i] = (1.f - z_)*nn + z_*hC[dt][i];
      }
    }

    __syncthreads();                 // bar1: gate readers of hb/cur done
    #pragma unroll
    for (int dt=0; dt<4; ++dt){
      const int cb = (w*4+dt)*16 + l4*4;
      u16x4 hw;
      #pragma unroll
      for (int i=0;i<4;++i) hw[i]=f2b(hC[dt][i]);
      *(u16x4*)(hb + l15*RS + cb) = hw;
    }
    if (it+1 < L){
      *(bf16x8*)(nxt + sr*RS + sc)   = sP0;
      *(bf16x8*)(nxt + sr*RS + sc+8) = sP1;
    }
    __syncthreads();                 // bar2: h + next x visible

    // ---- fused output projection (PO inline from L2; eo injected at kt==4) ----
    f32x4 Co[4];
    #pragma unroll
    for (int dt=0;dt<4;++dt) Co[dt]=f32x4{0,0,0,0};
    #pragma unroll
    for (int kt=0; kt<8; ++kt){
      bf16x8 hf = *(const bf16x8*)(hb + l15*RS + kt*32 + l4*8);
      if (kt==4){
        #pragma unroll
        for (int dt=0; dt<4; ++dt){
          const int d0 = (w*4+dt)*16 + l4*4;
          if (MODE==0){
            eo[dt] = ldf4<F32>(out, OT+((size_t)(n>>8)<<23)+((size_t)m<<16)+((size_t)(n&255)<<8)+d0);
          } else if (MODE==1){
            eo[dt] = ldf4<F32>(out, OT+((size_t)n<<16)+((size_t)m<<8)+d0);
          } else if (MODE==3){
            if (l15 < 8) eo[dt] = ldf4<F32>(A.xc, ((size_t)n<<15)+((size_t)m<<8)+d0);
          } else if (MODE==4){
            eo[dt] = ldf4<F32>(A.xf, ((size_t)n<<16)+((size_t)m<<8)+d0);
          }
        }
      }
      #pragma unroll
      for (int dt=0; dt<4; ++dt){
        bf16x8 wf = *(const bf16x8*)(PO + ((size_t)((w*4+dt)*8+kt)*64 + lane)*8);
        Co[dt] = __builtin_amdgcn_mfma_f32_16x16x32_bf16(wf, hf, Co[dt], 0,0,0);
      }
    }

    // x(it+2): issued after PV loads (youngest in FIFO -> drained next step)
    if (it+2 < L){
      const int m2 = (MODE==2)? (L-3-it) : (it+2);
      sN0 = stage_ld<MODE,F32>(A,out,n0,sr,m2,sc);
      sN1 = stage_ld<MODE,F32>(A,out,n0,sr,m2,sc+8);
    }

    // ---- epilogue: 4 coalesced f32x4 stores/RMWs ----
    #pragma unroll
    for (int dt=0; dt<4; ++dt){
      const int d0 = (w*4+dt)*16 + l4*4;
      f32x4 v = Co[dt];
      if (MODE==0){
        const size_t gix = ((size_t)(n>>8)<<23)+((size_t)m<<16)+((size_t)(n&255)<<8)+d0;
        #pragma unroll
        for (int i=0;i<4;++i) v[i]=qw(eo[dt][i]+v[i],SENT);
        stf4<F32>(out, OT+gix, v);
      } else if (MODE==1){
        const size_t gix = ((size_t)n<<16)+((size_t)m<<8)+d0;
        #pragma unroll
        for (int i=0;i<4;++i) v[i]=qw(eo[dt][i]+v[i],SENT);
        stf4<F32>(out, OT+gix, v);
      } else if (MODE==2){
        const size_t gix = ((size_t)n<<16)+((size_t)m<<8)+d0;
        #pragma unroll
        for (int i=0;i<4;++i) v[i]=qw(v[i],SENT);
        stf4<F32>(out, OF+gix, v);
      } else if (MODE==3){
        if (l15 < 8){
          const size_t lix = ((size_t)n<<15)+((size_t)m<<8)+d0;
          f32x4 bo = *(const f32x4*)&pbo[d0];
          #pragma unroll
          for (int i=0;i<4;++i) v[i]=qw(eo[dt][i]+bo[i]+v[i],SENT);
          stf4<F32>(out, OC+lix, v);
        }
      } else {
        const size_t gix = ((size_t)n<<16)+((size_t)m<<8)+d0;
        f32x4 bo = *(const f32x4*)&pbo[d0];
        #pragma unroll
        for (int i=0;i<4;++i) v[i]=qw(eo[dt][i]+bo[i]+v[i],SENT);
        stf4<F32>(out, OF+gix, v);
      }
    }

    sP0 = sN0; sP1 = sN1;
    u16* t_ = cur; cur = nxt; nxt = nx2; nx2 = t_;
  }
}

__global__ void __launch_bounds__(64) k_detect(const void* w, int* flagp){
  if (threadIdx.x==0 && blockIdx.x==0){
    const u32* p = (const u32*)w;
    int cnt = 0;
    for (int i=0;i<128;++i){
      const float v = b2f((u16)(p[i]&0xFFFFu));
      if (!(fabsf(v) <= 1e3f)) cnt++;
    }
    *flagp = (cnt>0) ? 1 : 0;
  }
}

#define GRU_LDS \
  __shared__ u16 wgt[4*8192]; \
  __shared__ u16 xb0[16*RS]; __shared__ u16 xb1[16*RS]; __shared__ u16 xb2[16*RS]; \
  __shared__ u16 hb[16*RS]; \
  __shared__ float pbA[768]; __shared__ float pbB[256]; __shared__ float pbo[256];

__global__ void __launch_bounds__(256) k1(Args A, const int* fl){   // gru_t(128) + gru_c(1)
  GRU_LDS
  const bool f32 = (*fl)!=0;
  if (blockIdx.x < 128){
    if (f32) grumm<0,true >(A,wgt,xb0,xb1,xb2,hb,pbA,pbB,pbo, blockIdx.x*16, 128);
    else     grumm<0,false>(A,wgt,xb0,xb1,xb2,hb,pbA,pbB,pbo, blockIdx.x*16, 128);
  } else {
    if (f32) grumm<3,true >(A,wgt,xb0,xb1,xb2,hb,pbA,pbB,pbo, 0, 128);
    else     grumm<3,false>(A,wgt,xb0,xb1,xb2,hb,pbA,pbB,pbo, 0, 128);
  }
}
__global__ void __launch_bounds__(256) k2(Args A, const int* fl){   // gru_ff(64) + gru_fb(64)
  GRU_LDS
  const bool f32 = (*fl)!=0;
  if (blockIdx.x < 64){
    if (f32) grumm<1,true >(A,wgt,xb0,xb1,xb2,hb,pbA,pbB,pbo, blockIdx.x*16, 256);
    else     grumm<1,false>(A,wgt,xb0,xb1,xb2,hb,pbA,pbB,pbo, blockIdx.x*16, 256);
  } else {
    if (f32) grumm<2,true >(A,wgt,xb0,xb1,xb2,hb,pbA,pbB,pbo, (blockIdx.x-64)*16, 256);
    else     grumm<2,false>(A,wgt,xb0,xb1,xb2,hb,pbA,pbB,pbo, (blockIdx.x-64)*16, 256);
  }
}
__global__ void __launch_bounds__(256) k3(Args A, const int* fl){   // gru_f(64)
  GRU_LDS
  if ((*fl)!=0) grumm<4,true >(A,wgt,xb0,xb1,xb2,hb,pbA,pbB,pbo, blockIdx.x*16, 256);
  else          grumm<4,false>(A,wgt,xb0,xb1,xb2,hb,pbA,pbB,pbo, blockIdx.x*16, 256);
}

template<bool F32>
__device__ void merge_body(const void* xf, void* out){
  const size_t i4 = ((size_t)blockIdx.x*256 + threadIdx.x)*4;   // < 67,108,864
  const int n  = (int)(i4 >> 16);
  const int d  = (int)(i4 & 255);
  f32x4 t; f32x4 a = ldf4<F32>(out, OT+i4), b = ldf4<F32>(out, OF+i4);
  f32x4 xfv = ldf4<F32>(xf, i4), cv = ldf4<F32>(out, OC+((size_t)n<<8)+d);
  f32x4 x;
  #pragma unroll
  for (int j=0;j<4;++j){ t[j]=qw(a[j]+b[j],6000.f); x[j]=qw(t[j]+xfv[j]+cv[j],6000.f); }
  stf4<F32>(out, OT+i4, t);
  stf4<F32>(out, OF+i4, x);
}
__global__ void __launch_bounds__(256) k_merge(const void* xf, void* out, const int* fl){
  if ((*fl)!=0) merge_body<true >(xf, out);
  else          merge_body<false>(xf, out);
}

template<bool F32>
__device__ void init_body(const void* xt, const void* bt, void* out){
  const size_t i4 = ((size_t)blockIdx.x*256 + threadIdx.x)*4;
  f32x4 x = ldf4<F32>(xt, i4), b = ldf4<F32>(bt, i4&255);
  f32x4 v;
  #pragma unroll
  for (int j=0;j<4;++j) v[j]=qw(x[j]+b[j],7000.f);
  stf4<F32>(out, OT+i4, v);
}
__global__ void __launch_bounds__(256) k_init(const void* xt, const void* bt, void* out, const int* fl){
  if ((*fl)!=0) init_body<true >(xt, bt, out);
  else          init_body<false>(xt, bt, out);
}

__global__ void __launch_bounds__(256) k_pack_g(const void* Wi, const void* Wh,
                                                u16* __restrict__ dst, const int* fl){
  const bool f32 = (*fl)!=0;
  const int t = blockIdx.x*256 + threadIdx.x;
  if (t >= 49152) return;
  const int lane = t & 63, kt = (t>>6)&15, ct = t>>10;
  const int col = ct*16 + (lane&15);
  const int kb  = kt*32 + ((lane>>4)<<3);
  #pragma unroll
  for (int j=0;j<8;++j){
    const int k = kb + j;
    const size_t six = (k<256) ? ((size_t)col*256 + k) : ((size_t)col*256 + k - 256);
    const void* src = (k<256) ? Wi : Wh;
    const float v = f32 ? ldsc<true>(src,six) : ldsc<false>(src,six);
    dst[(size_t)t*8+j] = f2b(v);
  }
}

__global__ void __launch_bounds__(256) k_pack_o(const void* Wsrc, int ldk, int koff,
                                                u16* __restrict__ dst, const int* fl){
  const bool f32 = (*fl)!=0;
  const int t = blockIdx.x*256 + threadIdx.x;
  if (t >= 8192) return;
  const int lane = t & 63, kt = (t>>6)&7, ct = t>>9;
  const int d  = ct*16 + (lane&15);
  const int kb = kt*32 + ((lane>>4)<<3) + koff;
  #pragma unroll
  for (int j=0;j<8;++j){
    const float v = f32 ? ldsc<true>(Wsrc,(size_t)d*ldk+kb+j) : ldsc<false>(Wsrc,(size_t)d*ldk+kb+j);
    dst[(size_t)t*8+j] = f2b(v);
  }
}

extern "C" void kernel_launch(void* const* d_in, const int* in_sizes, int n_in,
                              void* d_out, int out_size, void* d_ws, size_t ws_size,
                              hipStream_t stream){
  if (ws_size < 4600000) return;

  const void* x_time = d_in[0];
  const void* x_cent = d_in[1];
  const void* x_freq = d_in[2];
  const void *Wi[5], *Wh[5], *bi[5], *bh[5];
  for (int i=0;i<5;++i){
    Wi[i]=d_in[5+4*i]; Wh[i]=d_in[6+4*i]; bi[i]=d_in[7+4*i]; bh[i]=d_in[8+4*i];
  }
  const void* W_time=d_in[25]; const void* b_time=d_in[26];
  const void* W_cent=d_in[27]; const void* b_cent=d_in[28];
  const void* W_freq=d_in[29]; const void* b_freq=d_in[30];

  u16* wsu = (u16*)d_ws;
  u16* pg[5]; u16* po[5];
  size_t off = 0;
  for (int i=0;i<5;++i){ pg[i]=wsu+off; off += 49152*8; }
  for (int i=0;i<5;++i){ po[i]=wsu+off; off += 8192*8; }
  int* flagp = (int*)((char*)d_ws + 4587520);

  dim3 blk(256);
  k_detect<<<1, 64, 0, stream>>>(Wi[0], flagp);

  for (int i=0;i<5;++i) k_pack_g<<<192, blk, 0, stream>>>(Wi[i], Wh[i], pg[i], flagp);
  k_pack_o<<<32, blk, 0, stream>>>(W_time, 768,   0, po[0], flagp);
  k_pack_o<<<32, blk, 0, stream>>>(W_time, 768, 256, po[1], flagp);
  k_pack_o<<<32, blk, 0, stream>>>(W_time, 768, 512, po[2], flagp);
  k_pack_o<<<32, blk, 0, stream>>>(W_cent, 256,   0, po[3], flagp);
  k_pack_o<<<32, blk, 0, stream>>>(W_freq, 256,   0, po[4], flagp);

  k_init<<<65536, blk, 0, stream>>>(x_time, b_time, d_out, flagp);

  Args A;
  A.xt=x_time; A.xc=x_cent; A.xf=x_freq;
  for (int i=0;i<5;++i){ A.bi[i]=bi[i]; A.bh[i]=bh[i]; A.pg[i]=pg[i]; A.po[i]=po[i]; }
  A.b_cent=b_cent; A.b_freq=b_freq;
  A.out=d_out;

  k1<<<129, blk, 0, stream>>>(A, flagp);                 // t (RMW o_time) + c
  k2<<<128, blk, 0, stream>>>(A, flagp);                 // ff (RMW o_time) + fb (-> OF scratch)
  k_merge<<<65536, blk, 0, stream>>>(x_freq, d_out, flagp); // o_time final; OF := xfs
  k3<<<64, blk, 0, stream>>>(A, flagp);                  // f: stage xfs, write o_freq final
}

// Round 13
// 7165.050 us; speedup vs baseline: 2.2886x; 1.1740x over previous
//
#include <hip/hip_runtime.h>
#include <hip/hip_bf16.h>
#include <stdint.h>

typedef unsigned short u16;
typedef unsigned int u32;
typedef float f32x4 __attribute__((ext_vector_type(4)));
typedef short bf16x8 __attribute__((ext_vector_type(8)));
typedef u16 u16x4 __attribute__((ext_vector_type(4)));

__device__ __forceinline__ float b2f(u16 u){ union{u32 i; float f;} c; c.i=((u32)u)<<16; return c.f; }
__device__ __forceinline__ u16 f2b(float f){ __hip_bfloat16 h=__float2bfloat16(f); return *(u16*)&h; }
__device__ __forceinline__ float sigm(float x){ return 1.f/(1.f+__expf(-x)); }
__device__ __forceinline__ float tanh_(float x){ return 1.f - 2.f/(1.f+__expf(2.f*x)); }
__device__ __forceinline__ float qw(float v, float s){ return (v==v && fabsf(v)<1e30f) ? v : s; }

// async global->LDS DMA, 16B/lane (dest = wave-uniform base + lane*16, linear)
__device__ __forceinline__ void dma16(const void* g, void* l){
  __builtin_amdgcn_global_load_lds(
      (const __attribute__((address_space(1))) void*)g,
      (__attribute__((address_space(3))) void*)l, 16, 0, 0);
}

template<bool F32> __device__ __forceinline__ float ldsc(const void* p, size_t i){
  if constexpr (F32) return ((const float*)p)[i];
  else               return b2f(((const u16*)p)[i]);
}
template<bool F32> __device__ __forceinline__ f32x4 ldf4(const void* p, size_t i){
  if constexpr (F32) return *(const f32x4*)((const float*)p + i);
  else { u16x4 v = *(const u16x4*)((const u16*)p + i); f32x4 r;
         #pragma unroll
         for (int j=0;j<4;++j) r[j]=b2f(v[j]); return r; }
}
template<bool F32> __device__ __forceinline__ void stf4(void* p, size_t i, f32x4 v){
  if constexpr (F32) *(f32x4*)((float*)p + i) = v;
  else { u16x4 o;
         #pragma unroll
         for (int j=0;j<4;++j) o[j]=f2b(v[j]); *(u16x4*)((u16*)p + i) = o; }
}
template<bool F32> __device__ __forceinline__ bf16x8 ld8(const void* p, size_t ix){
  if constexpr (F32){
    const float* f = (const float*)p + ix;
    f32x4 a = *(const f32x4*)f, b = *(const f32x4*)(f+4);
    bf16x8 r;
    #pragma unroll
    for (int j=0;j<4;++j){ r[j]=(short)f2b(a[j]); r[4+j]=(short)f2b(b[j]); }
    return r;
  } else {
    return *(const bf16x8*)((const u16*)p + ix);
  }
}

constexpr size_t OT = 0;           // x_time   (8,128,256,256)
constexpr size_t OC = 67108864;    // x_central(8,128,256)
constexpr size_t OF = 67371008;    // x_freq   (8,128,256,256)
constexpr int RS = 264;            // LDS row stride (u16)

struct Args {
  const void *xt, *xc, *xf;
  const void *bi[5], *bh[5];
  const void *b_cent, *b_freq;
  const u16 *pg[5];                // packed gate weights  [48 ct][16 kt][64 lane][8]
  const u16 *po[5];                // packed out-proj wts  [16 ct][ 8 kt][64 lane][8]
  void *out;
};

template<int MODE, bool F32>
__device__ __forceinline__ bf16x8 stage_ld(const Args& A, const void* out, int n0, int r, int m, int c){
  if (MODE==0){ const int n=n0+r;
    return ld8<F32>(A.xt, ((size_t)(n>>8)<<23)+((size_t)m<<16)+((size_t)(n&255)<<8)+c); }
  else if (MODE==1 || MODE==2){ const int n=n0+r;
    return ld8<F32>(A.xt, ((size_t)n<<16)+((size_t)m<<8)+c); }
  else if (MODE==3){ const int n=n0+(r&7);
    return ld8<F32>(A.xc, ((size_t)n<<15)+((size_t)m<<8)+c); }
  else { const int n=n0+r;
    return ld8<F32>(out, OF+((size_t)n<<16)+((size_t)m<<8)+c); }
}

// 512-thread (8-wave, 2/SIMD) transposed-MFMA GRU, 16 rows/block.
// Wave w owns ct = g*16 + w*2 + dt (dt 0..1) per gate g.
// Gate weights stream through a wave-private 4-slot LDS ring via global_load_lds,
// paced by counted vmcnt(6) + sched_barrier(0x7F) (DS pinned, rest free).
// MODE: 0=t 1=ff 2=fb(rev -> OF scratch) 3=c 4=f(stage premerged OF)
template<int MODE, bool F32>
__device__ void grumm(const Args& A, u16* wgt, u16* xb0, u16* xb1, u16* hb,
                      float* pbA, float* pbB, float* pbo, int n0, int L){
  constexpr float SENT = 1000.f * (MODE+1);
  const u16* __restrict__ PG = A.pg[MODE];
  const u16* __restrict__ PO = A.po[MODE];
  void* const out = A.out;
  const int tid=threadIdx.x, lane=tid&63, w=tid>>6, l15=lane&15, l4=lane>>4;

  // biases -> LDS (fp32); h zero
  if (tid < 256){
    pbA[tid]     = ldsc<F32>(A.bi[MODE],tid)     + ldsc<F32>(A.bh[MODE],tid);
    pbA[256+tid] = ldsc<F32>(A.bi[MODE],256+tid) + ldsc<F32>(A.bh[MODE],256+tid);
    pbA[512+tid] = ldsc<F32>(A.bi[MODE],512+tid);
    pbB[tid]     = ldsc<F32>(A.bh[MODE],512+tid);
    pbo[tid]     = (MODE==3)? ldsc<F32>(A.b_cent,tid) : (MODE==4)? ldsc<F32>(A.b_freq,tid) : 0.f;
  }
  for (int i=tid; i<16*RS; i+=512) hb[i]=0;

  f32x4 hC[2];
  hC[0]=f32x4{0.f,0.f,0.f,0.f}; hC[1]=f32x4{0.f,0.f,0.f,0.f};

  // wave-private weight ring: 4 slots x 2 dt x 512 u16 (2KB/chunk, 8KB/wave)
  u16* mywgt = wgt + w*4096;
  auto issue_chunk = [&](int c, int s){
    const int g = c>>4, kt2 = c&15;
    #pragma unroll
    for (int dt=0; dt<2; ++dt){
      const int ct = g*16 + w*2 + dt;
      dma16(PG + ((size_t)(ct*16+kt2)*64 + lane)*8,
            mywgt + (s*2+dt)*512 + lane*8);
    }
  };

  // x staging: 32 threads/row, one bf16x8 (16B) each; double-buffered
  const int sr = tid>>5, sc = (tid&31)*8;
  {
    const int m0 = (MODE==2)? (L-1) : 0;
    bf16x8 t0 = stage_ld<MODE,F32>(A,out,n0,sr,m0,sc);
    *(bf16x8*)(xb0 + sr*RS + sc) = t0;
  }
  bf16x8 sP, sN;                 // x(it+1) in regs; x(it+2) in flight
  if (L>1){
    const int m1 = (MODE==2)? (L-2) : 1;
    sP = stage_ld<MODE,F32>(A,out,n0,sr,m1,sc);
  }
  // prologue: fill ring slots 0..3 with chunks 0..3 (8 loads outstanding)
  #pragma unroll
  for (int s=0; s<4; ++s) issue_chunk(s, s);
  __syncthreads();

  u16 *cur=xb0, *nxt=xb1;

  for (int it=0; it<L; ++it){
    const int m = (MODE==2)? (L-1-it) : it;
    const int n = n0 + l15;
    f32x4 eo[2];

    f32x4 Cr[2],Cz[2],Cnx[2],Cnh[2];
    #pragma unroll
    for (int dt=0;dt<2;++dt){ Cr[dt]=f32x4{0,0,0,0}; Cz[dt]=f32x4{0,0,0,0};
                              Cnx[dt]=f32x4{0,0,0,0}; Cnh[dt]=f32x4{0,0,0,0}; }

    // ---- gate phases; ring slot static; waits counted, DS pinned by sched_barrier ----
#define GPHASE(ACC, C0, NGRP, SRCSEL)                                          \
    _Pragma("unroll 1")                                                        \
    for (int grp=0; grp<(NGRP); ++grp){                                        \
      _Pragma("unroll")                                                        \
      for (int s=0; s<4; ++s){                                                 \
        const int c = (C0) + grp*4 + s;                                        \
        asm volatile("s_waitcnt vmcnt(6)");                                    \
        __builtin_amdgcn_sched_barrier(0x7F);                                  \
        const int kt = c & 15;                                                 \
        const u16* sld = (SRCSEL);                                             \
        bf16x8 ab = *(const bf16x8*)(sld + l15*RS + (kt&7)*32 + l4*8);         \
        bf16x8 f0 = *(const bf16x8*)(mywgt + (s*2+0)*512 + lane*8);            \
        bf16x8 f1 = *(const bf16x8*)(mywgt + (s*2+1)*512 + lane*8);            \
        { int rc = c + 4; if (rc >= 48) rc -= 48; issue_chunk(rc, s); }        \
        ACC[0] = __builtin_amdgcn_mfma_f32_16x16x32_bf16(f0, ab, ACC[0],0,0,0);\
        ACC[1] = __builtin_amdgcn_mfma_f32_16x16x32_bf16(f1, ab, ACC[1],0,0,0);\
      } }

    GPHASE(Cr,   0, 4, (kt<8)? cur : hb)   // g=0, kt 0..15
    GPHASE(Cz,  16, 4, (kt<8)? cur : hb)   // g=1
    GPHASE(Cnx, 32, 2, cur)                // g=2, kt 0..7 (x part)
    GPHASE(Cnh, 40, 2, hb)                 // g=2, kt 8..15 (h part)
#undef GPHASE

    // ---- activations ----
    #pragma unroll
    for (int dt=0; dt<2; ++dt){
      const int cb = (w*2+dt)*16 + l4*4;
      f32x4 bR  = *(const f32x4*)&pbA[cb];
      f32x4 bZ  = *(const f32x4*)&pbA[256+cb];
      f32x4 bNX = *(const f32x4*)&pbA[512+cb];
      f32x4 bNH = *(const f32x4*)&pbB[cb];
      #pragma unroll
      for (int i=0;i<4;++i){
        const float r_ = sigm(Cr[dt][i] + bR[i]);
        const float z_ = sigm(Cz[dt][i] + bZ[i]);
        const float nn = tanh_(Cnx[dt][i] + bNX[i] + r_*(Cnh[dt][i] + bNH[i]));
        hC[dt][i] = (1.f - z_)*nn + z_*hC[dt][i];
      }
    }

    __syncthreads();                 // bar1: gate readers of hb/cur done
    #pragma unroll
    for (int dt=0; dt<2; ++dt){
      const int cb = (w*2+dt)*16 + l4*4;
      u16x4 hw;
      #pragma unroll
      for (int i=0;i<4;++i) hw[i]=f2b(hC[dt][i]);
      *(u16x4*)(hb + l15*RS + cb) = hw;
    }
    if (it+1 < L) *(bf16x8*)(nxt + sr*RS + sc) = sP;   // nxt freed at bar1
    __syncthreads();                 // bar2: h + next x visible

    // ---- fused output projection (PO inline from L2; eo injected at kt==4) ----
    f32x4 Co[2];
    Co[0]=f32x4{0,0,0,0}; Co[1]=f32x4{0,0,0,0};
    #pragma unroll
    for (int kt=0; kt<8; ++kt){
      bf16x8 hf = *(const bf16x8*)(hb + l15*RS + kt*32 + l4*8);
      if (kt==4){
        #pragma unroll
        for (int dt=0; dt<2; ++dt){
          const int d0 = (w*2+dt)*16 + l4*4;
          if (MODE==0){
            eo[dt] = ldf4<F32>(out, OT+((size_t)(n>>8)<<23)+((size_t)m<<16)+((size_t)(n&255)<<8)+d0);
          } else if (MODE==1){
            eo[dt] = ldf4<F32>(out, OT+((size_t)n<<16)+((size_t)m<<8)+d0);
          } else if (MODE==3){
            if (l15 < 8) eo[dt] = ldf4<F32>(A.xc, ((size_t)n<<15)+((size_t)m<<8)+d0);
          } else if (MODE==4){
            eo[dt] = ldf4<F32>(A.xf, ((size_t)n<<16)+((size_t)m<<8)+d0);
          }
        }
      }
      #pragma unroll
      for (int dt=0; dt<2; ++dt){
        bf16x8 wf = *(const bf16x8*)(PO + ((size_t)((w*2+dt)*8+kt)*64 + lane)*8);
        Co[dt] = __builtin_amdgcn_mfma_f32_16x16x32_bf16(wf, hf, Co[dt], 0,0,0);
      }
    }

    // x(it+2): issued after PV loads (youngest in FIFO -> drained next step)
    if (it+2 < L){
      const int m2 = (MODE==2)? (L-3-it) : (it+2);
      sN = stage_ld<MODE,F32>(A,out,n0,sr,m2,sc);
    }

    // ---- epilogue: 2 coalesced f32x4 stores/RMWs ----
    #pragma unroll
    for (int dt=0; dt<2; ++dt){
      const int d0 = (w*2+dt)*16 + l4*4;
      f32x4 v = Co[dt];
      if (MODE==0){
        const size_t gix = ((size_t)(n>>8)<<23)+((size_t)m<<16)+((size_t)(n&255)<<8)+d0;
        #pragma unroll
        for (int i=0;i<4;++i) v[i]=qw(eo[dt][i]+v[i],SENT);
        stf4<F32>(out, OT+gix, v);
      } else if (MODE==1){
        const size_t gix = ((size_t)n<<16)+((size_t)m<<8)+d0;
        #pragma unroll
        for (int i=0;i<4;++i) v[i]=qw(eo[dt][i]+v[i],SENT);
        stf4<F32>(out, OT+gix, v);
      } else if (MODE==2){
        const size_t gix = ((size_t)n<<16)+((size_t)m<<8)+d0;
        #pragma unroll
        for (int i=0;i<4;++i) v[i]=qw(v[i],SENT);
        stf4<F32>(out, OF+gix, v);
      } else if (MODE==3){
        if (l15 < 8){
          const size_t lix = ((size_t)n<<15)+((size_t)m<<8)+d0;
          f32x4 bo = *(const f32x4*)&pbo[d0];
          #pragma unroll
          for (int i=0;i<4;++i) v[i]=qw(eo[dt][i]+bo[i]+v[i],SENT);
          stf4<F32>(out, OC+lix, v);
        }
      } else {
        const size_t gix = ((size_t)n<<16)+((size_t)m<<8)+d0;
        f32x4 bo = *(const f32x4*)&pbo[d0];
        #pragma unroll
        for (int i=0;i<4;++i) v[i]=qw(eo[dt][i]+bo[i]+v[i],SENT);
        stf4<F32>(out, OF+gix, v);
      }
    }

    sP = sN;
    u16* t_ = cur; cur = nxt; nxt = t_;
  }
}

__global__ void __launch_bounds__(64) k_detect(const void* w, int* flagp){
  if (threadIdx.x==0 && blockIdx.x==0){
    const u32* p = (const u32*)w;
    int cnt = 0;
    for (int i=0;i<128;++i){
      const float v = b2f((u16)(p[i]&0xFFFFu));
      if (!(fabsf(v) <= 1e3f)) cnt++;
    }
    *flagp = (cnt>0) ? 1 : 0;
  }
}

#define GRU_LDS \
  __shared__ u16 wgt[8*4096]; \
  __shared__ u16 xb0[16*RS]; __shared__ u16 xb1[16*RS]; \
  __shared__ u16 hb[16*RS]; \
  __shared__ float pbA[768]; __shared__ float pbB[256]; __shared__ float pbo[256];

__global__ void __launch_bounds__(512) k1(Args A, const int* fl){   // gru_t(128) + gru_c(1)
  GRU_LDS
  const bool f32 = (*fl)!=0;
  if (blockIdx.x < 128){
    if (f32) grumm<0,true >(A,wgt,xb0,xb1,hb,pbA,pbB,pbo, blockIdx.x*16, 128);
    else     grumm<0,false>(A,wgt,xb0,xb1,hb,pbA,pbB,pbo, blockIdx.x*16, 128);
  } else {
    if (f32) grumm<3,true >(A,wgt,xb0,xb1,hb,pbA,pbB,pbo, 0, 128);
    else     grumm<3,false>(A,wgt,xb0,xb1,hb,pbA,pbB,pbo, 0, 128);
  }
}
__global__ void __launch_bounds__(512) k2(Args A, const int* fl){   // gru_ff(64) + gru_fb(64)
  GRU_LDS
  const bool f32 = (*fl)!=0;
  if (blockIdx.x < 64){
    if (f32) grumm<1,true >(A,wgt,xb0,xb1,hb,pbA,pbB,pbo, blockIdx.x*16, 256);
    else     grumm<1,false>(A,wgt,xb0,xb1,hb,pbA,pbB,pbo, blockIdx.x*16, 256);
  } else {
    if (f32) grumm<2,true >(A,wgt,xb0,xb1,hb,pbA,pbB,pbo, (blockIdx.x-64)*16, 256);
    else     grumm<2,false>(A,wgt,xb0,xb1,hb,pbA,pbB,pbo, (blockIdx.x-64)*16, 256);
  }
}
__global__ void __launch_bounds__(512) k3(Args A, const int* fl){   // gru_f(64)
  GRU_LDS
  if ((*fl)!=0) grumm<4,true >(A,wgt,xb0,xb1,hb,pbA,pbB,pbo, blockIdx.x*16, 256);
  else          grumm<4,false>(A,wgt,xb0,xb1,hb,pbA,pbB,pbo, blockIdx.x*16, 256);
}

template<bool F32>
__device__ void merge_body(const void* xf, void* out){
  const size_t i4 = ((size_t)blockIdx.x*256 + threadIdx.x)*4;   // < 67,108,864
  const int n  = (int)(i4 >> 16);
  const int d  = (int)(i4 & 255);
  f32x4 t; f32x4 a = ldf4<F32>(out, OT+i4), b = ldf4<F32>(out, OF+i4);
  f32x4 xfv = ldf4<F32>(xf, i4), cv = ldf4<F32>(out, OC+((size_t)n<<8)+d);
  f32x4 x;
  #pragma unroll
  for (int j=0;j<4;++j){ t[j]=qw(a[j]+b[j],6000.f); x[j]=qw(t[j]+xfv[j]+cv[j],6000.f); }
  stf4<F32>(out, OT+i4, t);
  stf4<F32>(out, OF+i4, x);
}
__global__ void __launch_bounds__(256) k_merge(const void* xf, void* out, const int* fl){
  if ((*fl)!=0) merge_body<true >(xf, out);
  else          merge_body<false>(xf, out);
}

template<bool F32>
__device__ void init_body(const void* xt, const void* bt, void* out){
  const size_t i4 = ((size_t)blockIdx.x*256 + threadIdx.x)*4;
  f32x4 x = ldf4<F32>(xt, i4), b = ldf4<F32>(bt, i4&255);
  f32x4 v;
  #pragma unroll
  for (int j=0;j<4;++j) v[j]=qw(x[j]+b[j],7000.f);
  stf4<F32>(out, OT+i4, v);
}
__global__ void __launch_bounds__(256) k_init(const void* xt, const void* bt, void* out, const int* fl){
  if ((*fl)!=0) init_body<true >(xt, bt, out);
  else          init_body<false>(xt, bt, out);
}

__global__ void __launch_bounds__(256) k_pack_g(const void* Wi, const void* Wh,
                                                u16* __restrict__ dst, const int* fl){
  const bool f32 = (*fl)!=0;
  const int t = blockIdx.x*256 + threadIdx.x;
  if (t >= 49152) return;
  const int lane = t & 63, kt = (t>>6)&15, ct = t>>10;
  const int col = ct*16 + (lane&15);
  const int kb  = kt*32 + ((lane>>4)<<3);
  #pragma unroll
  for (int j=0;j<8;++j){
    const int k = kb + j;
    const size_t six = (k<256) ? ((size_t)col*256 + k) : ((size_t)col*256 + k - 256);
    const void* src = (k<256) ? Wi : Wh;
    const float v = f32 ? ldsc<true>(src,six) : ldsc<false>(src,six);
    dst[(size_t)t*8+j] = f2b(v);
  }
}

__global__ void __launch_bounds__(256) k_pack_o(const void* Wsrc, int ldk, int koff,
                                                u16* __restrict__ dst, const int* fl){
  const bool f32 = (*fl)!=0;
  const int t = blockIdx.x*256 + threadIdx.x;
  if (t >= 8192) return;
  const int lane = t & 63, kt = (t>>6)&7, ct = t>>9;
  const int d  = ct*16 + (lane&15);
  const int kb = kt*32 + ((lane>>4)<<3) + koff;
  #pragma unroll
  for (int j=0;j<8;++j){
    const float v = f32 ? ldsc<true>(Wsrc,(size_t)d*ldk+kb+j) : ldsc<false>(Wsrc,(size_t)d*ldk+kb+j);
    dst[(size_t)t*8+j] = f2b(v);
  }
}

extern "C" void kernel_launch(void* const* d_in, const int* in_sizes, int n_in,
                              void* d_out, int out_size, void* d_ws, size_t ws_size,
                              hipStream_t stream){
  if (ws_size < 4600000) return;

  const void* x_time = d_in[0];
  const void* x_cent = d_in[1];
  const void* x_freq = d_in[2];
  const void *Wi[5], *Wh[5], *bi[5], *bh[5];
  for (int i=0;i<5;++i){
    Wi[i]=d_in[5+4*i]; Wh[i]=d_in[6+4*i]; bi[i]=d_in[7+4*i]; bh[i]=d_in[8+4*i];
  }
  const void* W_time=d_in[25]; const void* b_time=d_in[26];
  const void* W_cent=d_in[27]; const void* b_cent=d_in[28];
  const void* W_freq=d_in[29]; const void* b_freq=d_in[30];

  u16* wsu = (u16*)d_ws;
  u16* pg[5]; u16* po[5];
  size_t off = 0;
  for (int i=0;i<5;++i){ pg[i]=wsu+off; off += 49152*8; }
  for (int i=0;i<5;++i){ po[i]=wsu+off; off += 8192*8; }
  int* flagp = (int*)((char*)d_ws + 4587520);

  dim3 blk(256);
  k_detect<<<1, 64, 0, stream>>>(Wi[0], flagp);

  for (int i=0;i<5;++i) k_pack_g<<<192, blk, 0, stream>>>(Wi[i], Wh[i], pg[i], flagp);
  k_pack_o<<<32, blk, 0, stream>>>(W_time, 768,   0, po[0], flagp);
  k_pack_o<<<32, blk, 0, stream>>>(W_time, 768, 256, po[1], flagp);
  k_pack_o<<<32, blk, 0, stream>>>(W_time, 768, 512, po[2], flagp);
  k_pack_o<<<32, blk, 0, stream>>>(W_cent, 256,   0, po[3], flagp);
  k_pack_o<<<32, blk, 0, stream>>>(W_freq, 256,   0, po[4], flagp);

  k_init<<<65536, blk, 0, stream>>>(x_time, b_time, d_out, flagp);

  Args A;
  A.xt=x_time; A.xc=x_cent; A.xf=x_freq;
  for (int i=0;i<5;++i){ A.bi[i]=bi[i]; A.bh[i]=bh[i]; A.pg[i]=pg[i]; A.po[i]=po[i]; }
  A.b_cent=b_cent; A.b_freq=b_freq;
  A.out=d_out;

  dim3 blk512(512);
  k1<<<129, blk512, 0, stream>>>(A, flagp);                 // t (RMW o_time) + c
  k2<<<128, blk512, 0, stream>>>(A, flagp);                 // ff (RMW o_time) + fb (-> OF scratch)
  k_merge<<<65536, blk, 0, stream>>>(x_freq, d_out, flagp); // o_time final; OF := xfs
  k3<<<64, blk512, 0, stream>>>(A, flagp);                  // f: stage xfs, write o_freq final
}